// Round 3
// baseline (424.064 us; speedup 1.0000x reference)
//
#include <hip/hip_runtime.h>
#include <hip/hip_bf16.h>

typedef __attribute__((ext_vector_type(8))) short bf16x8;
typedef __attribute__((ext_vector_type(4))) float f32x4;
typedef __attribute__((ext_vector_type(4))) int int4v;

#define DEV static __device__ __forceinline__

DEV float b2f(unsigned short u) { union { unsigned int i; float f; } c; c.i = ((unsigned int)u) << 16; return c.f; }
DEV unsigned short f2b(float f) {
  __hip_bfloat16 h = __float2bfloat16(f);
  unsigned short u; __builtin_memcpy(&u, &h, 2); return u;
}

// ---------------- transpose 1024x1024 fp32 -> bf16 (transposed) ----------------
__global__ __launch_bounds__(256) void k_transpose_w(const float* __restrict__ W,
                                                     unsigned short* __restrict__ Wt) {
  __shared__ float tile[32][33];
  const int tx = threadIdx.x & 31, ty = threadIdx.x >> 5;
  const int c0 = blockIdx.x * 32, r0 = blockIdx.y * 32;
#pragma unroll
  for (int i = 0; i < 4; ++i)
    tile[ty + i * 8][tx] = W[(size_t)(r0 + ty + i * 8) * 1024 + c0 + tx];
  __syncthreads();
#pragma unroll
  for (int i = 0; i < 4; ++i)
    Wt[(size_t)(c0 + ty + i * 8) * 1024 + r0 + tx] = f2b(tile[tx][ty + i * 8]);
}

// ---------------- per-batch sum of squares (x: [2][2048*1024] fp32) ----------------
__global__ __launch_bounds__(256) void k_reduce_sq(const float* __restrict__ x,
                                                   float* __restrict__ sums) {
  const int b = blockIdx.y;
  const float4* xb = (const float4*)(x + (size_t)b * 2097152);
  float s = 0.f;
  for (int i = blockIdx.x * 256 + threadIdx.x; i < 524288; i += 256 * gridDim.x) {
    float4 v = xb[i];
    s += v.x * v.x + v.y * v.y + v.z * v.z + v.w * v.w;
  }
  __shared__ float red[256];
  red[threadIdx.x] = s;
  __syncthreads();
  for (int st = 128; st > 0; st >>= 1) {
    if (threadIdx.x < st) red[threadIdx.x] += red[threadIdx.x + st];
    __syncthreads();
  }
  if (threadIdx.x == 0) atomicAdd(&sums[b], red[0]);
}

// ---------------- rmsnorm: out_bf16 = scale * x * rsqrt(sumsq/(S*D)) ----------------
__global__ __launch_bounds__(256) void k_rmsnorm(const float* __restrict__ x,
                                                 const float* __restrict__ scale,
                                                 const float* __restrict__ sums,
                                                 unsigned short* __restrict__ out) {
  const int idx = blockIdx.x * 256 + threadIdx.x;  // float4 group, 1M total
  const int e = idx * 4;
  const int m = e >> 10, d = e & 1023;
  const int b = m >> 11, s = m & 2047;
  const float inv = rsqrtf(sums[b] * (1.0f / 2097152.0f));
  float4 xv = *(const float4*)(x + (size_t)e);
  float4 sv = *(const float4*)(scale + (size_t)s * 1024 + d);
  ushort4 o;
  o.x = f2b(xv.x * sv.x * inv); o.y = f2b(xv.y * sv.y * inv);
  o.z = f2b(xv.z * sv.z * inv); o.w = f2b(xv.w * sv.w * inv);
  *(ushort4*)(out + e) = o;
}

// ---------------- GEMM: C[4096,N] = A[4096,1024] @ Bt[N,1024]^T, epilogues ----------------
// EPI 0: store bf16. EPI 1: fp32 store of (aux[row,col] + acc)  (residual). EPI 2: bf16 store of (acc + aux[col]) (bias).
template <int EPI>
__global__ __launch_bounds__(256) void k_gemm(const unsigned short* __restrict__ A,
                                              const unsigned short* __restrict__ Bt,
                                              void* __restrict__ Cout,
                                              const float* __restrict__ aux,
                                              const int N) {
  __shared__ short As[128 * 64];
  __shared__ short Bs[128 * 64];
  const int tid = threadIdx.x;
  const int w = tid >> 6, l = tid & 63;
  const int brow = blockIdx.y * 128, bcol = blockIdx.x * 128;
  const int wr = (w >> 1) * 64, wc = (w & 1) * 64;
  const int ch_r = tid >> 3, ch_g = tid & 7;
  f32x4 acc[4][4] = {};
  const short* Ag = (const short*)A;
  const short* Bg = (const short*)Bt;
  for (int k0 = 0; k0 < 1024; k0 += 64) {
    int4v ra[4], rb[4];
#pragma unroll
    for (int p = 0; p < 4; ++p) {
      const int row = p * 32 + ch_r;
      ra[p] = *(const int4v*)(Ag + (size_t)(brow + row) * 1024 + k0 + ch_g * 8);
      rb[p] = *(const int4v*)(Bg + (size_t)(bcol + row) * 1024 + k0 + ch_g * 8);
    }
    __syncthreads();
#pragma unroll
    for (int p = 0; p < 4; ++p) {
      const int row = p * 32 + ch_r;
      const int sidx = row * 64 + ((ch_g ^ (row & 7)) * 8);
      *(int4v*)(As + sidx) = ra[p];
      *(int4v*)(Bs + sidx) = rb[p];
    }
    __syncthreads();
#pragma unroll
    for (int kk = 0; kk < 2; ++kk) {
      const int g0 = kk * 4 + (l >> 4);
      bf16x8 af[4], bfr[4];
#pragma unroll
      for (int m = 0; m < 4; ++m) {
        const int row = wr + m * 16 + (l & 15);
        af[m] = *(const bf16x8*)(As + row * 64 + ((g0 ^ (row & 7)) * 8));
      }
#pragma unroll
      for (int n = 0; n < 4; ++n) {
        const int col = wc + n * 16 + (l & 15);
        bfr[n] = *(const bf16x8*)(Bs + col * 64 + ((g0 ^ (col & 7)) * 8));
      }
#pragma unroll
      for (int m = 0; m < 4; ++m)
#pragma unroll
        for (int n = 0; n < 4; ++n)
          acc[m][n] = __builtin_amdgcn_mfma_f32_16x16x32_bf16(af[m], bfr[n], acc[m][n], 0, 0, 0);
    }
  }
  const int rr = (l >> 4) * 4, cc = l & 15;
#pragma unroll
  for (int m = 0; m < 4; ++m)
#pragma unroll
    for (int n = 0; n < 4; ++n) {
      const int col = bcol + wc + n * 16 + cc;
#pragma unroll
      for (int j = 0; j < 4; ++j) {
        const int row = brow + wr + m * 16 + rr + j;
        float v = acc[m][n][j];
        if (EPI == 0) {
          ((unsigned short*)Cout)[(size_t)row * N + col] = f2b(v);
        } else if (EPI == 1) {
          ((float*)Cout)[(size_t)row * N + col] = aux[(size_t)row * N + col] + v;
        } else {
          ((unsigned short*)Cout)[(size_t)row * N + col] = f2b(v + aux[col]);
        }
      }
    }
}

// ---------------- RoPE in place over qkv [4096][3072] bf16 (pairs as uint) ----------------
__global__ __launch_bounds__(256) void k_rope(unsigned int* __restrict__ qkv32) {
  const int p = blockIdx.x * 256 + threadIdx.x;  // pair index, 6291456 total
  const int m = p / 1536;
  const int pc = p - m * 1536;
  const int s = m & 2047;
  const int i = pc & 511;
  // theta = 10000^(-2*(i-1)/1024) = exp(-(i-1) * 2*ln(10000)/1024)
  const float theta = expf(-((float)i - 1.0f) * 0.017988946039016f);
  const float ang = (float)s * theta;
  float sn, cs;
  sincosf(ang, &sn, &cs);
  unsigned int v = qkv32[p];
  float xe = b2f((unsigned short)(v & 0xffffu));
  float xo = b2f((unsigned short)(v >> 16));
  float oe = xe * cs + xo * sn;
  float oo = -xe * sn + xo * cs;
  qkv32[p] = (unsigned int)f2b(oe) | ((unsigned int)f2b(oo) << 16);
}

// ---------------- V transpose: qkv v-section -> vt[b*16+h][64 d][2048 s] bf16 ----------------
__global__ __launch_bounds__(256) void k_transpose_v(const unsigned short* __restrict__ qkv,
                                                     unsigned short* __restrict__ vt) {
  __shared__ unsigned short tile[32][33];
  const int tx = threadIdx.x & 31, ty = threadIdx.x >> 5;
  const int bh = blockIdx.z;
  const int b = bh >> 4, h = bh & 15;
  const int d0 = blockIdx.x * 32, s0 = blockIdx.y * 32;
#pragma unroll
  for (int i = 0; i < 4; ++i)
    tile[ty + i * 8][tx] = qkv[(size_t)(b * 2048 + s0 + ty + i * 8) * 3072 + 2048 + h * 64 + d0 + tx];
  __syncthreads();
#pragma unroll
  for (int i = 0; i < 4; ++i)
    vt[((size_t)bh * 64 + d0 + ty + i * 8) * 2048 + s0 + tx] = tile[tx][ty + i * 8];
}

// ---------------- flash attention with ALiBi + causal ----------------
// grid (S/64=32 qt, H=16, B=2), 256 threads = 4 waves, wave w owns 16 q rows.
__global__ __launch_bounds__(256) void k_attn(const unsigned short* __restrict__ qkv,
                                              const unsigned short* __restrict__ vt,
                                              unsigned short* __restrict__ o) {
  __shared__ short Ks[64 * 64];
  __shared__ short Vs[64 * 64];
  __shared__ short Ps[4][16 * 80];
  const int qt = blockIdx.x, h = blockIdx.y, b = blockIdx.z;
  const int tid = threadIdx.x, w = tid >> 6, l = tid & 63;
  const int q0 = qt * 64, qw = q0 + w * 16;
  const short* qg = (const short*)qkv;
  bf16x8 aq[2];
  {
    const int row = qw + (l & 15);
    const short* base = qg + (size_t)(b * 2048 + row) * 3072 + h * 64 + (l >> 4) * 8;
    aq[0] = *(const bf16x8*)(base);
    aq[1] = *(const bf16x8*)(base + 32);
  }
  const float slope = exp2f(-0.5f * (float)(h + 1));
  f32x4 oacc[4] = {};
  float mrun[4] = {-1e30f, -1e30f, -1e30f, -1e30f};
  float lrun[4] = {0.f, 0.f, 0.f, 0.f};
  short* Pw = &Ps[w][0];
  const int st_r = tid >> 3, st_g = tid & 7;
  for (int kvt = 0; kvt <= qt; ++kvt) {
    const int kv0 = kvt * 64;
    __syncthreads();
#pragma unroll
    for (int p = 0; p < 2; ++p) {
      const int r = p * 32 + st_r;
      const int sidx = r * 64 + ((st_g ^ (r & 7)) * 8);
      *(int4v*)(Ks + sidx) =
          *(const int4v*)(qg + (size_t)(b * 2048 + kv0 + r) * 3072 + 1024 + h * 64 + st_g * 8);
      *(int4v*)(Vs + sidx) =
          *(const int4v*)((const short*)vt + ((size_t)(b * 16 + h) * 64 + r) * 2048 + kv0 + st_g * 8);
    }
    __syncthreads();
    f32x4 sacc[4] = {};
#pragma unroll
    for (int kk = 0; kk < 2; ++kk) {
      const int g0 = kk * 4 + (l >> 4);
#pragma unroll
      for (int n = 0; n < 4; ++n) {
        const int col = n * 16 + (l & 15);
        bf16x8 bk = *(const bf16x8*)(Ks + col * 64 + ((g0 ^ (col & 7)) * 8));
        sacc[n] = __builtin_amdgcn_mfma_f32_16x16x32_bf16(aq[kk], bk, sacc[n], 0, 0, 0);
      }
    }
    float pv[4][4];
    float rm[4] = {-3e30f, -3e30f, -3e30f, -3e30f};
#pragma unroll
    for (int n = 0; n < 4; ++n) {
      const int kvg = kv0 + n * 16 + (l & 15);
#pragma unroll
      for (int j = 0; j < 4; ++j) {
        const int qrow = qw + (l >> 4) * 4 + j;
        float v;
        if (kvg <= qrow) v = sacc[n][j] * 0.125f + slope * (float)(kvg - qrow);
        else v = -1e30f;
        pv[n][j] = v;
        rm[j] = fmaxf(rm[j], v);
      }
    }
#pragma unroll
    for (int j = 0; j < 4; ++j) {
      rm[j] = fmaxf(rm[j], __shfl_xor(rm[j], 1));
      rm[j] = fmaxf(rm[j], __shfl_xor(rm[j], 2));
      rm[j] = fmaxf(rm[j], __shfl_xor(rm[j], 4));
      rm[j] = fmaxf(rm[j], __shfl_xor(rm[j], 8));
    }
    float corr[4], rs[4];
#pragma unroll
    for (int j = 0; j < 4; ++j) {
      const float mn = fmaxf(mrun[j], rm[j]);
      corr[j] = __expf(mrun[j] - mn);
      mrun[j] = mn;
      rs[j] = 0.f;
    }
#pragma unroll
    for (int n = 0; n < 4; ++n)
#pragma unroll
      for (int j = 0; j < 4; ++j) {
        const float e = __expf(pv[n][j] - mrun[j]);
        pv[n][j] = e;
        rs[j] += e;
      }
#pragma unroll
    for (int j = 0; j < 4; ++j) {
      rs[j] += __shfl_xor(rs[j], 1);
      rs[j] += __shfl_xor(rs[j], 2);
      rs[j] += __shfl_xor(rs[j], 4);
      rs[j] += __shfl_xor(rs[j], 8);
      lrun[j] = lrun[j] * corr[j] + rs[j];
    }
#pragma unroll
    for (int n = 0; n < 4; ++n)
#pragma unroll
      for (int j = 0; j < 4; ++j) oacc[n][j] *= corr[j];
#pragma unroll
    for (int n = 0; n < 4; ++n)
#pragma unroll
      for (int j = 0; j < 4; ++j)
        Pw[((l >> 4) * 4 + j) * 80 + n * 16 + (l & 15)] = (short)f2b(pv[n][j]);
#pragma unroll
    for (int kk2 = 0; kk2 < 2; ++kk2) {
      bf16x8 pf = *(const bf16x8*)(Pw + (l & 15) * 80 + kk2 * 32 + (l >> 4) * 8);
#pragma unroll
      for (int n = 0; n < 4; ++n) {
        const int dr = n * 16 + (l & 15);
        bf16x8 vf = *(const bf16x8*)(Vs + dr * 64 + (((kk2 * 4 + (l >> 4)) ^ (dr & 7)) * 8));
        oacc[n] = __builtin_amdgcn_mfma_f32_16x16x32_bf16(pf, vf, oacc[n], 0, 0, 0);
      }
    }
  }
#pragma unroll
  for (int n = 0; n < 4; ++n)
#pragma unroll
    for (int j = 0; j < 4; ++j) {
      const int row = qw + (l >> 4) * 4 + j;
      const int col = h * 64 + n * 16 + (l & 15);
      o[(size_t)(b * 2048 + row) * 1024 + col] = f2b(oacc[n][j] / lrun[j]);
    }
}

// ---------------- final: out = x1 + swish(g)*lin ----------------
__global__ __launch_bounds__(256) void k_final(const float* __restrict__ x1,
                                               const unsigned short* __restrict__ gl,
                                               const float* __restrict__ beta,
                                               float* __restrict__ out) {
  const int idx = blockIdx.x * 256 + threadIdx.x;
  const int e = idx * 4;
  const int m = e >> 10, d = e & 1023;
  const float bt = beta[0];
  ushort4 gu = *(const ushort4*)(gl + (size_t)m * 2048 + d);
  ushort4 lu = *(const ushort4*)(gl + (size_t)m * 2048 + 1024 + d);
  float4 xv = *(const float4*)(x1 + e);
  float g0 = b2f(gu.x), g1 = b2f(gu.y), g2 = b2f(gu.z), g3 = b2f(gu.w);
  float l0 = b2f(lu.x), l1 = b2f(lu.y), l2 = b2f(lu.z), l3 = b2f(lu.w);
  float4 r;
  r.x = xv.x + g0 / (1.f + __expf(-bt * g0)) * l0;
  r.y = xv.y + g1 / (1.f + __expf(-bt * g1)) * l1;
  r.z = xv.z + g2 / (1.f + __expf(-bt * g2)) * l2;
  r.w = xv.w + g3 / (1.f + __expf(-bt * g3)) * l3;
  *(float4*)(out + e) = r;
}

extern "C" void kernel_launch(void* const* d_in, const int* in_sizes, int n_in,
                              void* d_out, int out_size, void* d_ws, size_t ws_size,
                              hipStream_t stream) {
  (void)in_sizes; (void)n_in; (void)out_size; (void)ws_size;
  const float* x      = (const float*)d_in[0];
  const float* Wq     = (const float*)d_in[1];
  const float* Wk     = (const float*)d_in[2];
  const float* Wv     = (const float*)d_in[3];
  const float* Wo     = (const float*)d_in[4];
  const float* scale1 = (const float*)d_in[5];
  const float* scale2 = (const float*)d_in[6];
  const float* W1     = (const float*)d_in[7];
  const float* b1     = (const float*)d_in[8];
  const float* Wg     = (const float*)d_in[9];
  const float* bg     = (const float*)d_in[10];
  const float* Wl     = (const float*)d_in[11];
  const float* bl     = (const float*)d_in[12];
  const float* beta   = (const float*)d_in[13];
  float* out = (float*)d_out;

  char* ws = (char*)d_ws;
  float* sums         = (float*)ws;                       // 256 B (4 used)
  float* bgl          = (float*)(ws + 256);               // 2048 floats
  unsigned short* WT  = (unsigned short*)(ws + 16384);                 // 3M bf16 (6 MB)
  unsigned short* h   = (unsigned short*)(ws + 16384 + 6291456);       // 4M bf16 (8 MB)
  unsigned short* qkv = (unsigned short*)((char*)h + 8388608);         // 12M bf16 (24 MB)
  unsigned short* vt  = (unsigned short*)((char*)qkv + 25165824);      // 4M bf16 (8 MB)
  unsigned short* ob  = (unsigned short*)((char*)vt + 8388608);        // 4M bf16 (8 MB)
  float* x1           = (float*)((char*)ob + 8388608);                 // 4M fp32 (16 MB)
  unsigned short* t1  = qkv;                 // reuse (qkv dead after attention)
  unsigned short* gl  = qkv + 4194304;       // reuse, 8M bf16

  hipMemsetAsync(sums, 0, 256, stream);

  // --- attention sublayer ---
  k_transpose_w<<<dim3(32, 32), 256, 0, stream>>>(Wq, WT);
  k_transpose_w<<<dim3(32, 32), 256, 0, stream>>>(Wk, WT + 1048576);
  k_transpose_w<<<dim3(32, 32), 256, 0, stream>>>(Wv, WT + 2097152);
  k_reduce_sq<<<dim3(256, 2), 256, 0, stream>>>(x, sums);
  k_rmsnorm<<<4096, 256, 0, stream>>>(x, scale1, sums, h);
  k_gemm<0><<<dim3(24, 32), 256, 0, stream>>>(h, WT, (void*)qkv, nullptr, 3072);
  k_rope<<<24576, 256, 0, stream>>>((unsigned int*)qkv);
  k_transpose_v<<<dim3(2, 64, 32), 256, 0, stream>>>(qkv, vt);
  k_attn<<<dim3(32, 16, 2), 256, 0, stream>>>(qkv, vt, ob);
  k_transpose_w<<<dim3(32, 32), 256, 0, stream>>>(Wo, WT);
  k_gemm<1><<<dim3(8, 32), 256, 0, stream>>>(ob, WT, (void*)x1, x, 1024);

  // --- FFN sublayer ---
  k_reduce_sq<<<dim3(256, 2), 256, 0, stream>>>(x1, sums + 2);
  k_rmsnorm<<<4096, 256, 0, stream>>>(x1, scale2, sums + 2, h);
  k_transpose_w<<<dim3(32, 32), 256, 0, stream>>>(W1, WT);
  k_gemm<2><<<dim3(8, 32), 256, 0, stream>>>(h, WT, (void*)t1, b1, 1024);
  k_transpose_w<<<dim3(32, 32), 256, 0, stream>>>(Wg, WT);
  k_transpose_w<<<dim3(32, 32), 256, 0, stream>>>(Wl, WT + 1048576);
  hipMemcpyAsync(bgl, bg, 4096, hipMemcpyDeviceToDevice, stream);
  hipMemcpyAsync(bgl + 1024, bl, 4096, hipMemcpyDeviceToDevice, stream);
  k_gemm<2><<<dim3(16, 32), 256, 0, stream>>>(t1, WT, (void*)gl, bgl, 2048);
  k_final<<<4096, 256, 0, stream>>>(x1, gl, beta, out);
}